// Round 7
// baseline (235.145 us; speedup 1.0000x reference)
//
#include <hip/hip_runtime.h>

#define N_NODES 50000
#define N_EDGES 800000
#define F_IN    512
#define HID     128
#define OUT_F   20
#define CAP     48           // max in-degree capacity (mean 16, 8 sigma headroom)

#define BM  64

typedef __bf16 bf16x8 __attribute__((ext_vector_type(8)));
typedef float  f32x4  __attribute__((ext_vector_type(4)));

// ---------------- CSR-by-destination via fixed-capacity buckets ----------------

__global__ void k_zero(int* __restrict__ cursor) {
    int i = blockIdx.x * blockDim.x + threadIdx.x;
    if (i < N_NODES) cursor[i] = i * CAP;
}

// one atomic per edge; payload packed into a single 8B store
__global__ void k_fillb(const int* __restrict__ row, const int* __restrict__ col,
                        const float* __restrict__ ew, int* __restrict__ cursor,
                        uint2* __restrict__ packed) {
    int e = blockIdx.x * blockDim.x + threadIdx.x;
    if (e < N_EDGES) {
        int c = col[e];
        int pos = atomicAdd(&cursor[c], 1);
        packed[pos] = make_uint2((unsigned)row[e], __float_as_uint(ew[e]));
    }
}

// deg = 1 + sum(w) over bucket (sequential, no atomics); dinv = rsqrt(deg); cnt saved
__global__ void k_degdinv(const int* __restrict__ cursor, const uint2* __restrict__ packed,
                          int* __restrict__ cnt, float* __restrict__ dinv) {
    int i = blockIdx.x * blockDim.x + threadIdx.x;
    if (i < N_NODES) {
        int n = cursor[i] - i * CAP;
        cnt[i] = n;
        const uint2* seg = packed + (size_t)i * CAP;
        float d = 1.0f;
        for (int k = 0; k < n; ++k) d += __uint_as_float(seg[k].y);
        dinv[i] = rsqrtf(d);   // d >= 1 always
    }
}

// ---------------- W1 -> frag-ready permuted bf16 layout ----------------
// w1p index: (((kk*4 + g)*128 + cc)*8 + j), where B-frag elem j of lane group g
// covers k = kk*32 + g*4 + (j&3) + 16*(j>>2), column cc.
// Thread id = k*128+cc (coalesced W1 read); dest scattered (2B) but tiny kernel.

__global__ void k_cvt_w1p(const float* __restrict__ W1, __bf16* __restrict__ w1p) {
    int gidx = blockIdx.x * blockDim.x + threadIdx.x;   // = k*HID + cc
    if (gidx < F_IN * HID) {
        int k  = gidx >> 7;
        int cc = gidx & (HID - 1);
        int kk = k >> 5;
        int r  = k & 31;
        int g  = (r & 15) >> 2;
        int j  = (r & 3) + ((r >> 4) << 2);
        w1p[((((size_t)kk * 4 + g) * 128 + cc) << 3) + j] = (__bf16)W1[gidx];
    }
}

// ---------------- layer 1 GEMM (MFMA bf16): hb = bf16(x @ W1) ----------------
// Barrier-free, LDS-free. 64x128 block tile, 4 waves 2x2, wave = 32x64 (2x4 frags).
// A: direct fp32 global reads (2 guarded float4 per mi) -> reg convert to bf16.
//    Lanes {l, l+16, l+32, l+48} jointly read a full 64B line of one x row.
// B: one 16B load per frag from frag-ready w1p (L2-resident), 256B-coalesced per group.
// Double-buffered frag registers; compiler hoists next-kk loads over MFMA.

__global__ __launch_bounds__(256) void k_gemm1_mfma(const float* __restrict__ x,
                                                    const __bf16* __restrict__ w1p,
                                                    __bf16* __restrict__ hb) {
    const int tid  = threadIdx.x;
    const int lane = tid & 63;
    const int wid  = tid >> 6;
    const int wm   = wid >> 1;            // row half (32)
    const int wn   = wid & 1;             // col half (64)
    const int r0   = blockIdx.x * BM;
    const int g    = lane >> 4;           // k-group 0..3
    const int l15  = lane & 15;

    f32x4 acc[2][4] = {};
    bf16x8 a[2][2], b[2][4];

    auto loadA = [&](int kk, int buf) {
#pragma unroll
        for (int mi = 0; mi < 2; ++mi) {
            int rowi = r0 + wm * 32 + mi * 16 + l15;
            float4 lo = make_float4(0.f, 0.f, 0.f, 0.f);
            float4 hi = make_float4(0.f, 0.f, 0.f, 0.f);
            if (rowi < N_NODES) {
                const float* px = x + (size_t)rowi * F_IN + kk * 32 + g * 4;
                lo = *(const float4*)px;          // k = g*4 + 0..3
                hi = *(const float4*)(px + 16);   // k = g*4 + 16..19
            }
            union { __bf16 h[8]; bf16x8 v; } u;
            u.h[0] = (__bf16)lo.x; u.h[1] = (__bf16)lo.y;
            u.h[2] = (__bf16)lo.z; u.h[3] = (__bf16)lo.w;
            u.h[4] = (__bf16)hi.x; u.h[5] = (__bf16)hi.y;
            u.h[6] = (__bf16)hi.z; u.h[7] = (__bf16)hi.w;
            a[buf][mi] = u.v;
        }
    };
    auto loadB = [&](int kk, int buf) {
#pragma unroll
        for (int ni = 0; ni < 4; ++ni) {
            int cc = wn * 64 + ni * 16 + l15;
            b[buf][ni] = *(const bf16x8*)(w1p + ((((size_t)kk * 4 + g) * 128 + cc) << 3));
        }
    };

    loadA(0, 0);
    loadB(0, 0);
#pragma unroll
    for (int kk = 0; kk < 16; ++kk) {
        int cur = kk & 1;
        if (kk < 15) { loadA(kk + 1, cur ^ 1); loadB(kk + 1, cur ^ 1); }
#pragma unroll
        for (int mi = 0; mi < 2; ++mi)
#pragma unroll
            for (int ni = 0; ni < 4; ++ni)
                acc[mi][ni] = __builtin_amdgcn_mfma_f32_16x16x32_bf16(
                    a[cur][mi], b[cur][ni], acc[mi][ni], 0, 0, 0);
    }

    // epilogue: C/D col=lane&15, row=(lane>>4)*4+reg
#pragma unroll
    for (int mi = 0; mi < 2; ++mi) {
        int rb = r0 + wm * 32 + mi * 16 + (g << 2);
#pragma unroll
        for (int rr = 0; rr < 4; ++rr) {
            int gr = rb + rr;
            if (gr < N_NODES) {
#pragma unroll
                for (int ni = 0; ni < 4; ++ni) {
                    int cc = wn * 64 + ni * 16 + l15;
                    hb[(size_t)gr * HID + cc] = (__bf16)acc[mi][ni][rr];
                }
            }
        }
    }
}

// ---------------- layer 1 aggregation: 1 wave per node, bf16x2 packed, on-the-fly norm --

__device__ inline float blo(unsigned v) { union { unsigned u; float f; } c; c.u = v << 16; return c.f; }
__device__ inline float bhi(unsigned v) { union { unsigned u; float f; } c; c.u = v & 0xffff0000u; return c.f; }

__global__ __launch_bounds__(128) void k_agg1(const uint2* __restrict__ packed,
                                              const int* __restrict__ cnt,
                                              const __bf16* __restrict__ hb,
                                              const float* __restrict__ dinv,
                                              const float* __restrict__ b1,
                                              float* __restrict__ h1) {
    __shared__ int   sr[2][64];
    __shared__ float sn[2][64];
    const int w    = threadIdx.x >> 6;
    const int lane = threadIdx.x & 63;
    const int c    = blockIdx.x * 2 + w;
    const unsigned* hbu = (const unsigned*)hb;

    float dic = dinv[c];
    unsigned sv = hbu[((size_t)c << 6) + lane];
    float a0 = dic * dic * blo(sv);
    float a1 = dic * dic * bhi(sv);
    int n = cnt[c];
    const uint2* seg = packed + (size_t)c * CAP;
    for (int base = 0; base < n; base += 64) {
        int m = n - base; if (m > 64) m = 64;
        if (lane < m) {                       // wave-synchronous, no barrier
            uint2 pv = seg[base + lane];
            sr[w][lane] = (int)pv.x;
            sn[w][lane] = __uint_as_float(pv.y) * dinv[pv.x] * dic;
        }
        for (int t = 0; t < m; ++t) {
            float nm = sn[w][t];
            unsigned v = hbu[((size_t)sr[w][t] << 6) + lane];
            a0 = fmaf(nm, blo(v), a0);
            a1 = fmaf(nm, bhi(v), a1);
        }
    }
    float2 bb = *(const float2*)(b1 + 2 * lane);
    a0 += bb.x; a1 += bb.y;
    float2 o2;
    o2.x = a0 > 0.f ? a0 : 0.f;
    o2.y = a1 > 0.f ? a1 : 0.f;
    *(float2*)(h1 + ((size_t)c << 7) + 2 * lane) = o2;
}

// ---------------- layer 2 GEMM: h2 = h1 @ W2  (50000x128 @ 128x20) ----------------

__global__ __launch_bounds__(256) void k_gemm2(const float* __restrict__ h1,
                                               const float* __restrict__ W2,
                                               float* __restrict__ h2) {
    int g = blockIdx.x * blockDim.x + threadIdx.x;
    int i = g >> 5;
    int j = g & 31;
    if (i >= N_NODES || j >= OUT_F) return;
    float acc = 0.f;
    const float* hr = h1 + (size_t)i * HID;
    for (int k = 0; k < HID; ++k) acc = fmaf(hr[k], W2[k * OUT_F + j], acc);
    h2[(size_t)i * OUT_F + j] = acc;
}

// ---------------- layer 2 aggregation (on-the-fly norm) ----------------

__global__ __launch_bounds__(256) void k_agg2(const uint2* __restrict__ packed,
                                              const int* __restrict__ cnt,
                                              const float* __restrict__ h2,
                                              const float* __restrict__ dinv,
                                              const float* __restrict__ b2,
                                              float* __restrict__ out) {
    int g = blockIdx.x * blockDim.x + threadIdx.x;
    int c = g >> 5;
    int j = g & 31;
    if (c >= N_NODES || j >= OUT_F) return;
    float dic = dinv[c];
    float acc = dic * dic * h2[(size_t)c * OUT_F + j] + b2[j];
    int n = cnt[c];
    const uint2* seg = packed + (size_t)c * CAP;
    for (int k = 0; k < n; ++k) {
        uint2 pv = seg[k];                    // broadcast across lanes
        float nm = __uint_as_float(pv.y) * dinv[pv.x] * dic;
        acc = fmaf(nm, h2[(size_t)pv.x * OUT_F + j], acc);
    }
    out[(size_t)c * OUT_F + j] = acc;
}

// ---------------- launch ----------------

extern "C" void kernel_launch(void* const* d_in, const int* in_sizes, int n_in,
                              void* d_out, int out_size, void* d_ws, size_t ws_size,
                              hipStream_t stream) {
    const float* x  = (const float*)d_in[0];
    const int*   ei = (const int*)d_in[1];       // [2][E]
    const float* ew = (const float*)d_in[2];
    const float* W1 = (const float*)d_in[3];
    const float* b1 = (const float*)d_in[4];
    const float* W2 = (const float*)d_in[5];
    const float* b2 = (const float*)d_in[6];
    float* out = (float*)d_out;

    const int* row = ei;
    const int* col = ei + N_EDGES;

    char* p = (char*)d_ws;
    float* dinv   = (float*)p;  p += (size_t)N_NODES * 4;
    float* h1     = (float*)p;  p += (size_t)N_NODES * HID * 4;
    float* h2     = (float*)p;  p += (size_t)N_NODES * OUT_F * 4;
    __bf16* hb    = (__bf16*)p; p += (size_t)N_NODES * HID * 2;
    __bf16* w1p   = (__bf16*)p; p += (size_t)F_IN * HID * 2;
    int* cursor   = (int*)p;    p += (size_t)N_NODES * 4;
    int* cnt      = (int*)p;    p += (size_t)N_NODES * 4;
    uint2* packed = (uint2*)p;  p += (size_t)N_NODES * CAP * 8;

    // CSR build: one atomic pass into fixed-capacity buckets
    k_zero<<<(N_NODES + 255) / 256, 256, 0, stream>>>(cursor);
    k_fillb<<<(N_EDGES + 255) / 256, 256, 0, stream>>>(row, col, ew, cursor, packed);
    k_degdinv<<<(N_NODES + 255) / 256, 256, 0, stream>>>(cursor, packed, cnt, dinv);

    // layer 1
    k_cvt_w1p<<<(F_IN * HID + 255) / 256, 256, 0, stream>>>(W1, w1p);
    k_gemm1_mfma<<<(N_NODES + BM - 1) / BM, 256, 0, stream>>>(x, w1p, hb);
    k_agg1<<<N_NODES / 2, 128, 0, stream>>>(packed, cnt, hb, dinv, b1, h1);

    // layer 2
    k_gemm2<<<(N_NODES * 32 + 255) / 256, 256, 0, stream>>>(h1, W2, h2);
    k_agg2<<<(N_NODES * 32 + 255) / 256, 256, 0, stream>>>(packed, cnt, h2, dinv, b2, out);
}

// Round 8
// 231.770 us; speedup vs baseline: 1.0146x; 1.0146x over previous
//
#include <hip/hip_runtime.h>

#define N_NODES 50000
#define N_EDGES 800000
#define F_IN    512
#define HID     128
#define OUT_F   20
#define CAP     48           // max in-degree capacity (mean 16, 8 sigma headroom)

#define BM  32

typedef __bf16 bf16x8 __attribute__((ext_vector_type(8)));
typedef float  f32x4  __attribute__((ext_vector_type(4)));

// ---------------- CSR-by-destination via fixed-capacity buckets ----------------

// one atomic per edge; payload packed into a single 8B store
__global__ void k_fillb(const int* __restrict__ row, const int* __restrict__ col,
                        const float* __restrict__ ew, int* __restrict__ cursor,
                        uint2* __restrict__ packed) {
    int e = blockIdx.x * blockDim.x + threadIdx.x;
    if (e < N_EDGES) {
        int c = col[e];
        int pos = atomicAdd(&cursor[c], 1);
        packed[pos] = make_uint2((unsigned)row[e], __float_as_uint(ew[e]));
    }
}

// deg = 1 + sum(w) over bucket (sequential, no atomics); dinv = rsqrt(deg); cnt saved
__global__ void k_degdinv(const int* __restrict__ cursor, const uint2* __restrict__ packed,
                          int* __restrict__ cnt, float* __restrict__ dinv) {
    int i = blockIdx.x * blockDim.x + threadIdx.x;
    if (i < N_NODES) {
        int n = cursor[i] - i * CAP;
        cnt[i] = n;
        const uint2* seg = packed + (size_t)i * CAP;
        float d = 1.0f;
        for (int k = 0; k < n; ++k) d += __uint_as_float(seg[k].y);
        dinv[i] = rsqrtf(d);   // d >= 1 always
    }
}

// ---------------- prep: W1 -> frag-ready permuted bf16 + cursor init (fused) ----------
// w1p index: (((kk*4 + g)*128 + cc)*8 + j); B-frag elem j of lane group g covers
// k = kk*32 + g*4 + (j&3) + 16*(j>>2), column cc.

__global__ void k_prep(const float* __restrict__ W1, __bf16* __restrict__ w1p,
                       int* __restrict__ cursor) {
    int gidx = blockIdx.x * blockDim.x + threadIdx.x;
    if (gidx < F_IN * HID) {
        int k  = gidx >> 7;
        int cc = gidx & (HID - 1);
        int kk = k >> 5;
        int r  = k & 31;
        int g  = (r & 15) >> 2;
        int j  = (r & 3) + ((r >> 4) << 2);
        w1p[((((size_t)kk * 4 + g) * 128 + cc) << 3) + j] = (__bf16)W1[gidx];
    }
    if (gidx < N_NODES) cursor[gidx] = gidx * CAP;
}

// ---------------- layer 1 GEMM (MFMA bf16): hb = bf16(x @ W1) ----------------
// Barrier-free, LDS-free. 32x128 block tile (1563 blocks -> ~6 waves/SIMD),
// 4 waves 2x2, wave = 16x64 (1x4 frags of 16x16x32), prefetch depth 2 (3 rotating
// register buffers, fully unrolled kk loop -> static indices).
// A: direct fp32 global reads (2 guarded float4) -> reg convert to bf16.
//    Lanes {l, l+16, l+32, l+48} jointly read a full 64B line of one x row.
// B: one 16B load per frag from frag-ready w1p (L2-resident), 256B-coalesced per group.

__global__ __launch_bounds__(256) void k_gemm1_mfma(const float* __restrict__ x,
                                                    const __bf16* __restrict__ w1p,
                                                    __bf16* __restrict__ hb) {
    const int tid  = threadIdx.x;
    const int lane = tid & 63;
    const int wid  = tid >> 6;
    const int wm   = wid >> 1;            // row block of 16
    const int wn   = wid & 1;             // col block of 64
    const int r0   = blockIdx.x * BM;
    const int g    = lane >> 4;           // k-group 0..3
    const int l15  = lane & 15;

    const int rowi = r0 + wm * 16 + l15;
    const bool valid = rowi < N_NODES;
    const float* px = x + (size_t)rowi * F_IN + g * 4;

    f32x4 acc[4] = {};
    bf16x8 a[3];
    bf16x8 b[3][4];

    auto loadA = [&](int kk, int buf) {
        float4 lo = make_float4(0.f, 0.f, 0.f, 0.f);
        float4 hi = make_float4(0.f, 0.f, 0.f, 0.f);
        if (valid) {
            lo = *(const float4*)(px + kk * 32);        // k = g*4 + 0..3
            hi = *(const float4*)(px + kk * 32 + 16);   // k = g*4 + 16..19
        }
        union { __bf16 h[8]; bf16x8 v; } u;
        u.h[0] = (__bf16)lo.x; u.h[1] = (__bf16)lo.y;
        u.h[2] = (__bf16)lo.z; u.h[3] = (__bf16)lo.w;
        u.h[4] = (__bf16)hi.x; u.h[5] = (__bf16)hi.y;
        u.h[6] = (__bf16)hi.z; u.h[7] = (__bf16)hi.w;
        a[buf] = u.v;
    };
    auto loadB = [&](int kk, int buf) {
#pragma unroll
        for (int ni = 0; ni < 4; ++ni) {
            int cc = wn * 64 + ni * 16 + l15;
            b[buf][ni] = *(const bf16x8*)(w1p + ((((size_t)kk * 4 + g) * 128 + cc) << 3));
        }
    };

    loadA(0, 0); loadB(0, 0);
    loadA(1, 1); loadB(1, 1);
#pragma unroll
    for (int kk = 0; kk < 16; ++kk) {
        const int cur = kk % 3;
        if (kk < 14) {
            const int nb = (kk + 2) % 3;
            loadA(kk + 2, nb);
            loadB(kk + 2, nb);
        }
#pragma unroll
        for (int ni = 0; ni < 4; ++ni)
            acc[ni] = __builtin_amdgcn_mfma_f32_16x16x32_bf16(
                a[cur], b[cur][ni], acc[ni], 0, 0, 0);
    }

    // epilogue: C/D col=lane&15, row=(lane>>4)*4+reg
    const int rb = r0 + wm * 16 + (g << 2);
#pragma unroll
    for (int rr = 0; rr < 4; ++rr) {
        int gr = rb + rr;
        if (gr < N_NODES) {
#pragma unroll
            for (int ni = 0; ni < 4; ++ni) {
                int cc = wn * 64 + ni * 16 + l15;
                hb[(size_t)gr * HID + cc] = (__bf16)acc[ni][rr];
            }
        }
    }
}

// ---------------- layer 1 aggregation: 1 wave per node, bf16x2 packed, on-the-fly norm --

__device__ inline float blo(unsigned v) { union { unsigned u; float f; } c; c.u = v << 16; return c.f; }
__device__ inline float bhi(unsigned v) { union { unsigned u; float f; } c; c.u = v & 0xffff0000u; return c.f; }

__global__ __launch_bounds__(128) void k_agg1(const uint2* __restrict__ packed,
                                              const int* __restrict__ cnt,
                                              const __bf16* __restrict__ hb,
                                              const float* __restrict__ dinv,
                                              const float* __restrict__ b1,
                                              float* __restrict__ h1) {
    __shared__ int   sr[2][64];
    __shared__ float sn[2][64];
    const int w    = threadIdx.x >> 6;
    const int lane = threadIdx.x & 63;
    const int c    = blockIdx.x * 2 + w;
    const unsigned* hbu = (const unsigned*)hb;

    float dic = dinv[c];
    unsigned sv = hbu[((size_t)c << 6) + lane];
    float a0 = dic * dic * blo(sv);
    float a1 = dic * dic * bhi(sv);
    int n = cnt[c];
    const uint2* seg = packed + (size_t)c * CAP;
    for (int base = 0; base < n; base += 64) {
        int m = n - base; if (m > 64) m = 64;
        if (lane < m) {                       // wave-synchronous, no barrier
            uint2 pv = seg[base + lane];
            sr[w][lane] = (int)pv.x;
            sn[w][lane] = __uint_as_float(pv.y) * dinv[pv.x] * dic;
        }
        for (int t = 0; t < m; ++t) {
            float nm = sn[w][t];
            unsigned v = hbu[((size_t)sr[w][t] << 6) + lane];
            a0 = fmaf(nm, blo(v), a0);
            a1 = fmaf(nm, bhi(v), a1);
        }
    }
    float2 bb = *(const float2*)(b1 + 2 * lane);
    a0 += bb.x; a1 += bb.y;
    float2 o2;
    o2.x = a0 > 0.f ? a0 : 0.f;
    o2.y = a1 > 0.f ? a1 : 0.f;
    *(float2*)(h1 + ((size_t)c << 7) + 2 * lane) = o2;
}

// ---------------- layer 2 GEMM: h2 = h1 @ W2  (50000x128 @ 128x20) ----------------

__global__ __launch_bounds__(256) void k_gemm2(const float* __restrict__ h1,
                                               const float* __restrict__ W2,
                                               float* __restrict__ h2) {
    int g = blockIdx.x * blockDim.x + threadIdx.x;
    int i = g >> 5;
    int j = g & 31;
    if (i >= N_NODES || j >= OUT_F) return;
    float acc = 0.f;
    const float* hr = h1 + (size_t)i * HID;
    for (int k = 0; k < HID; ++k) acc = fmaf(hr[k], W2[k * OUT_F + j], acc);
    h2[(size_t)i * OUT_F + j] = acc;
}

// ---------------- layer 2 aggregation (on-the-fly norm) ----------------

__global__ __launch_bounds__(256) void k_agg2(const uint2* __restrict__ packed,
                                              const int* __restrict__ cnt,
                                              const float* __restrict__ h2,
                                              const float* __restrict__ dinv,
                                              const float* __restrict__ b2,
                                              float* __restrict__ out) {
    int g = blockIdx.x * blockDim.x + threadIdx.x;
    int c = g >> 5;
    int j = g & 31;
    if (c >= N_NODES || j >= OUT_F) return;
    float dic = dinv[c];
    float acc = dic * dic * h2[(size_t)c * OUT_F + j] + b2[j];
    int n = cnt[c];
    const uint2* seg = packed + (size_t)c * CAP;
    for (int k = 0; k < n; ++k) {
        uint2 pv = seg[k];                    // broadcast across lanes
        float nm = __uint_as_float(pv.y) * dinv[pv.x] * dic;
        acc = fmaf(nm, h2[(size_t)pv.x * OUT_F + j], acc);
    }
    out[(size_t)c * OUT_F + j] = acc;
}

// ---------------- launch ----------------

extern "C" void kernel_launch(void* const* d_in, const int* in_sizes, int n_in,
                              void* d_out, int out_size, void* d_ws, size_t ws_size,
                              hipStream_t stream) {
    const float* x  = (const float*)d_in[0];
    const int*   ei = (const int*)d_in[1];       // [2][E]
    const float* ew = (const float*)d_in[2];
    const float* W1 = (const float*)d_in[3];
    const float* b1 = (const float*)d_in[4];
    const float* W2 = (const float*)d_in[5];
    const float* b2 = (const float*)d_in[6];
    float* out = (float*)d_out;

    const int* row = ei;
    const int* col = ei + N_EDGES;

    char* p = (char*)d_ws;
    float* dinv   = (float*)p;  p += (size_t)N_NODES * 4;
    float* h1     = (float*)p;  p += (size_t)N_NODES * HID * 4;
    float* h2     = (float*)p;  p += (size_t)N_NODES * OUT_F * 4;
    __bf16* hb    = (__bf16*)p; p += (size_t)N_NODES * HID * 2;
    __bf16* w1p   = (__bf16*)p; p += (size_t)F_IN * HID * 2;
    int* cursor   = (int*)p;    p += (size_t)N_NODES * 4;
    int* cnt      = (int*)p;    p += (size_t)N_NODES * 4;
    uint2* packed = (uint2*)p;  p += (size_t)N_NODES * CAP * 8;

    // prep (W1 permute + cursor init), then CSR build: one atomic pass into buckets
    k_prep<<<(F_IN * HID + 255) / 256, 256, 0, stream>>>(W1, w1p, cursor);
    k_fillb<<<(N_EDGES + 255) / 256, 256, 0, stream>>>(row, col, ew, cursor, packed);
    k_degdinv<<<(N_NODES + 255) / 256, 256, 0, stream>>>(cursor, packed, cnt, dinv);

    // layer 1
    k_gemm1_mfma<<<(N_NODES + BM - 1) / BM, 256, 0, stream>>>(x, w1p, hb);
    k_agg1<<<N_NODES / 2, 128, 0, stream>>>(packed, cnt, hb, dinv, b1, h1);

    // layer 2
    k_gemm2<<<(N_NODES * 32 + 255) / 256, 256, 0, stream>>>(h1, W2, h2);
    k_agg2<<<(N_NODES * 32 + 255) / 256, 256, 0, stream>>>(packed, cnt, h2, dinv, b2, out);
}